// Round 8
// baseline (269.177 us; speedup 1.0000x reference)
//
#include <hip/hip_runtime.h>
#include <hip/hip_bf16.h>

#define N_NODES 100000
#define N_EDGES 3200000
#define N_GRAPHS 256

#define NBUCK 782                 // ceil(N_NODES / 128) buckets (col >> 7)
#define SORT_ITEMS 8192           // edges per block in hist/scatter passes
#define NB_SORT ((N_EDGES + SORT_ITEMS - 1) / SORT_ITEMS)   // 391
#define ROW_MASK 131071           // 2^17 - 1 (N_NODES < 2^17)
#define BCAP 4608                 // LDS edge capacity per bucket in build (mean 4092, +8 sigma)

__device__ __forceinline__ float bfl(int d) {  // low bf16 of dword -> f32
    return __uint_as_float(((unsigned)d) << 16);
}
__device__ __forceinline__ float bfh(int d) {  // high bf16 of dword -> f32
    return __uint_as_float(((unsigned)d) & 0xffff0000u);
}
__device__ __forceinline__ unsigned short f2bf(float f) {
    __hip_bfloat16 b = __float2bfloat16(f);
    return *(unsigned short*)&b;
}

// ---------------- pass 1: per-block LDS histogram -> global bucket totals ----------------
__global__ __launch_bounds__(256) void hist_kernel(const int* __restrict__ col,
                                                   int* __restrict__ btot) {
    __shared__ int h[NBUCK];
    int tid = threadIdx.x;
    for (int i = tid; i < NBUCK; i += 256) h[i] = 0;
    __syncthreads();
    int base = blockIdx.x * SORT_ITEMS + tid * 4;
    #pragma unroll
    for (int l = 0; l < SORT_ITEMS / 1024; ++l) {
        int e = base + l * 1024;
        if (e < N_EDGES) {
            int4 c4 = *(const int4*)&col[e];
            atomicAdd(&h[c4.x >> 7], 1);
            atomicAdd(&h[c4.y >> 7], 1);
            atomicAdd(&h[c4.z >> 7], 1);
            atomicAdd(&h[c4.w >> 7], 1);
        }
    }
    __syncthreads();
    for (int i = tid; i < NBUCK; i += 256) {
        int c = h[i];
        if (c) atomicAdd(&btot[i], c);
    }
}

// ---------------- scan bucket totals -> bstart (exclusive), init gcur ----------------
__global__ __launch_bounds__(256) void scan_buckets_kernel(const int* __restrict__ btot,
                                                           int* __restrict__ bstart,
                                                           int* __restrict__ gcur) {
    __shared__ int s[256];
    int tid = threadIdx.x;
    int i0 = tid * 4;
    int c0 = (i0 + 0 < NBUCK) ? btot[i0 + 0] : 0;
    int c1 = (i0 + 1 < NBUCK) ? btot[i0 + 1] : 0;
    int c2 = (i0 + 2 < NBUCK) ? btot[i0 + 2] : 0;
    int c3 = (i0 + 3 < NBUCK) ? btot[i0 + 3] : 0;
    int sum = c0 + c1 + c2 + c3;
    s[tid] = sum;
    __syncthreads();
    for (int d = 1; d < 256; d <<= 1) {
        int x = (tid >= d) ? s[tid - d] : 0;
        __syncthreads();
        s[tid] += x;
        __syncthreads();
    }
    int excl = s[tid] - sum;
    if (i0 + 0 < NBUCK) { bstart[i0 + 0] = excl;              gcur[i0 + 0] = excl; }
    if (i0 + 1 < NBUCK) { bstart[i0 + 1] = excl + c0;         gcur[i0 + 1] = excl + c0; }
    if (i0 + 2 < NBUCK) { bstart[i0 + 2] = excl + c0 + c1;    gcur[i0 + 2] = excl + c0 + c1; }
    if (i0 + 3 < NBUCK) { bstart[i0 + 3] = excl + c0 + c1 + c2; gcur[i0 + 3] = excl + c0 + c1 + c2; }
    if (tid == 255) bstart[NBUCK] = N_EDGES;
}

// ---------------- pass 2: LDS counting-sort per block, run-coalesced global write ----------------
// rw2 entry: { row | (col&127)<<17 , ew }
__global__ __launch_bounds__(256) void scatter_sort_kernel(const int* __restrict__ col,
                                                           const int* __restrict__ row,
                                                           const float* __restrict__ ew,
                                                           int* __restrict__ gcur,
                                                           int2* __restrict__ rw2) {
    __shared__ int lcnt[NBUCK];
    __shared__ int lofs[NBUCK];
    __shared__ int lcur[NBUCK];
    __shared__ int gbase[NBUCK];
    __shared__ int ps[256];
    __shared__ int2 buf[SORT_ITEMS];
    int tid = threadIdx.x;
    for (int i = tid; i < NBUCK; i += 256) lcnt[i] = 0;
    __syncthreads();
    int base = blockIdx.x * SORT_ITEMS + tid * 4;
    // pass 1: local counts
    #pragma unroll
    for (int l = 0; l < SORT_ITEMS / 1024; ++l) {
        int e = base + l * 1024;
        if (e < N_EDGES) {
            int4 c4 = *(const int4*)&col[e];
            atomicAdd(&lcnt[c4.x >> 7], 1);
            atomicAdd(&lcnt[c4.y >> 7], 1);
            atomicAdd(&lcnt[c4.z >> 7], 1);
            atomicAdd(&lcnt[c4.w >> 7], 1);
        }
    }
    __syncthreads();
    // local exclusive scan of lcnt -> lofs (4 per thread)
    int i0 = tid * 4;
    int c0 = (i0 + 0 < NBUCK) ? lcnt[i0 + 0] : 0;
    int c1 = (i0 + 1 < NBUCK) ? lcnt[i0 + 1] : 0;
    int c2 = (i0 + 2 < NBUCK) ? lcnt[i0 + 2] : 0;
    int c3 = (i0 + 3 < NBUCK) ? lcnt[i0 + 3] : 0;
    int sum = c0 + c1 + c2 + c3;
    ps[tid] = sum;
    __syncthreads();
    for (int d = 1; d < 256; d <<= 1) {
        int x = (tid >= d) ? ps[tid - d] : 0;
        __syncthreads();
        ps[tid] += x;
        __syncthreads();
    }
    int excl = ps[tid] - sum;
    if (i0 + 0 < NBUCK) lofs[i0 + 0] = excl;
    if (i0 + 1 < NBUCK) lofs[i0 + 1] = excl + c0;
    if (i0 + 2 < NBUCK) lofs[i0 + 2] = excl + c0 + c1;
    if (i0 + 3 < NBUCK) lofs[i0 + 3] = excl + c0 + c1 + c2;
    __syncthreads();
    // reserve global runs, init local cursors
    for (int i = tid; i < NBUCK; i += 256) {
        int c = lcnt[i];
        gbase[i] = c ? atomicAdd(&gcur[i], c) : 0;
        lcur[i] = lofs[i];
    }
    __syncthreads();
    // pass 2: re-load edges (L2-hot), place into LDS in sorted order
    #pragma unroll
    for (int l = 0; l < SORT_ITEMS / 1024; ++l) {
        int e = base + l * 1024;
        if (e < N_EDGES) {
            int4 c4 = *(const int4*)&col[e];
            int4 r4 = *(const int4*)&row[e];
            float4 w4 = *(const float4*)&ew[e];
            int p0 = atomicAdd(&lcur[c4.x >> 7], 1);
            int p1 = atomicAdd(&lcur[c4.y >> 7], 1);
            int p2 = atomicAdd(&lcur[c4.z >> 7], 1);
            int p3 = atomicAdd(&lcur[c4.w >> 7], 1);
            buf[p0] = make_int2(r4.x | ((c4.x & 127) << 17), __float_as_int(w4.x));
            buf[p1] = make_int2(r4.y | ((c4.y & 127) << 17), __float_as_int(w4.y));
            buf[p2] = make_int2(r4.z | ((c4.z & 127) << 17), __float_as_int(w4.z));
            buf[p3] = make_int2(r4.w | ((c4.w & 127) << 17), __float_as_int(w4.w));
        }
    }
    __syncthreads();
    // copy out: consecutive i -> consecutive dst within each bucket run
    int total = min(SORT_ITEMS, N_EDGES - blockIdx.x * SORT_ITEMS);
    for (int i = tid; i < total; i += 256) {
        int lo = 0, hi = NBUCK - 1;
        while (lo < hi) { int mid = (lo + hi + 1) >> 1; if (lofs[mid] <= i) lo = mid; else hi = mid - 1; }
        int dst = gbase[lo] + (i - lofs[lo]);
        rw2[dst] = buf[i];
    }
}

// ---------------- pass 3: per-bucket CSR build, LDS-staged, coalesced csr write ----------------
__global__ __launch_bounds__(256) void build_kernel(const int* __restrict__ bstart,
                                                    const int2* __restrict__ rw2,
                                                    int* __restrict__ off,
                                                    int* __restrict__ cnt,
                                                    float* __restrict__ dinv,
                                                    int2* __restrict__ csr) {
    int b = blockIdx.x;
    int tid = threadIdx.x;
    int begin = bstart[b];
    int end = bstart[b + 1];
    int len = end - begin;
    __shared__ int2 ebuf[BCAP];
    __shared__ int2 obuf[BCAP];
    __shared__ int lcnt[128];
    __shared__ float ldeg[128];
    __shared__ int s[256];
    __shared__ int curo[128];
    if (tid < 128) { lcnt[tid] = 0; ldeg[tid] = 0.f; }
    __syncthreads();
    // pass 1: load edges, stage into LDS, count + weighted degree per local node
    for (int i = tid; i < len; i += 1024) {
        #pragma unroll
        for (int u = 0; u < 4; ++u) {
            int ii = i + u * 256;
            if (ii < len) {
                int2 a = rw2[begin + ii];
                if (ii < BCAP) ebuf[ii] = a;
                int loc = a.x >> 17;
                atomicAdd(&lcnt[loc], 1);
                atomicAdd(&ldeg[loc], __int_as_float(a.y));
            }
        }
    }
    __syncthreads();
    // exclusive scan of 128 counts
    int v = (tid < 128) ? lcnt[tid] : 0;
    s[tid] = v;
    __syncthreads();
    for (int d = 1; d < 128; d <<= 1) {
        int x = (tid >= d && tid < 128) ? s[tid - d] : 0;
        __syncthreads();
        if (tid < 128) s[tid] += x;
        __syncthreads();
    }
    if (tid < 128) {
        int excl = s[tid] - v;
        int node = (b << 7) + tid;
        if (node < N_NODES) {
            off[node] = begin + excl;
            cnt[node] = v;
            dinv[node] = rsqrtf(1.0f + ldeg[tid]);
        }
        curo[tid] = excl;  // local positions
    }
    __syncthreads();
    // pass 2: scatter into LDS output buffer (local), overflow straight to global
    for (int i = tid; i < len; i += 1024) {
        #pragma unroll
        for (int u = 0; u < 4; ++u) {
            int ii = i + u * 256;
            if (ii < len) {
                int2 a = (ii < BCAP) ? ebuf[ii] : rw2[begin + ii];
                int loc = a.x >> 17;
                int p = atomicAdd(&curo[loc], 1);
                int2 w = make_int2(a.x & ROW_MASK, a.y);
                if (p < BCAP) obuf[p] = w; else csr[begin + p] = w;
            }
        }
    }
    __syncthreads();
    // coalesced linear copy
    int lim = min(len, BCAP);
    for (int i = tid; i < lim; i += 256) csr[begin + i] = obuf[i];
}

// ------- tiled f32 GEMM, bf16 output: H[r,:] = bf16( (X@W)[r,:] * scale[r] ) -------
template <int IN, int OUT, int ROWS>
__global__ __launch_bounds__(256) void gemm_bf16_kernel(const float* __restrict__ X,
                                                        const float* __restrict__ W,
                                                        const float* __restrict__ scale,
                                                        unsigned short* __restrict__ H, int n) {
    constexpr int BK = 16;
    constexpr int TX = OUT / 4;   // thread cols
    constexpr int TY = ROWS / 8;  // thread rows
    static_assert(TX * TY == 256, "block must be 256 threads");
    __shared__ float xsT[BK][ROWS + 4];
    __shared__ float ws[BK][OUT + 4];
    int tid = threadIdx.x;
    int tx = tid % TX, ty = tid / TX;
    int r0 = blockIdx.x * ROWS;
    float acc[8][4] = {};
    for (int k0 = 0; k0 < IN; k0 += BK) {
        constexpr int XL = (ROWS * BK) / (256 * 4);
        #pragma unroll
        for (int l = 0; l < XL; ++l) {
            int t = tid + l * 256;
            int rr = t >> 2;
            int kp = (t & 3) * 4;
            float4 v = make_float4(0.f, 0.f, 0.f, 0.f);
            int gr = r0 + rr;
            if (gr < n) v = *(const float4*)&X[(size_t)gr * IN + k0 + kp];
            xsT[kp + 0][rr] = v.x;
            xsT[kp + 1][rr] = v.y;
            xsT[kp + 2][rr] = v.z;
            xsT[kp + 3][rr] = v.w;
        }
        constexpr int WL = (BK * OUT) / 4;
        if (WL == 256 || tid < WL) {
            int kr = tid / TX;
            int cp = (tid % TX) * 4;
            float4 v = *(const float4*)&W[(size_t)(k0 + kr) * OUT + cp];
            *(float4*)&ws[kr][cp] = v;
        }
        __syncthreads();
        #pragma unroll
        for (int kk = 0; kk < BK; ++kk) {
            float4 a0 = *(const float4*)&xsT[kk][ty * 8];
            float4 a1 = *(const float4*)&xsT[kk][ty * 8 + 4];
            float4 b = *(const float4*)&ws[kk][tx * 4];
            float av[8] = {a0.x, a0.y, a0.z, a0.w, a1.x, a1.y, a1.z, a1.w};
            float bv[4] = {b.x, b.y, b.z, b.w};
            #pragma unroll
            for (int i = 0; i < 8; ++i) {
                #pragma unroll
                for (int j = 0; j < 4; ++j) acc[i][j] = fmaf(av[i], bv[j], acc[i][j]);
            }
        }
        __syncthreads();
    }
    #pragma unroll
    for (int i = 0; i < 8; ++i) {
        int gr = r0 + ty * 8 + i;
        if (gr < n) {
            float sc = scale[gr];
            ushort4 o;
            o.x = f2bf(acc[i][0] * sc);
            o.y = f2bf(acc[i][1] * sc);
            o.z = f2bf(acc[i][2] * sc);
            o.w = f2bf(acc[i][3] * sc);
            *(ushort4*)&H[(size_t)gr * OUT + tx * 4] = o;
        }
    }
}

// ---------------- aggregation conv1: 64 feats, wave per node ----------------
// Wave = 8 edge-slots x 8 feat-blocks; 4 gather groups in flight.
__global__ __launch_bounds__(256) void agg1_kernel(const int2* __restrict__ csr,
                                                   const int* __restrict__ off,
                                                   const int* __restrict__ cnt,
                                                   const float* __restrict__ dinv,
                                                   const unsigned short* __restrict__ h1t,
                                                   const float* __restrict__ b1,
                                                   float* __restrict__ h1p) {
    int lane = threadIdx.x & 63;
    int node = blockIdx.x * 4 + (threadIdx.x >> 6);
    int es = lane >> 3;   // edge slot 0..7
    int fb = lane & 7;    // feat block 0..7 (8 feats each)
    int s = off[node], c = cnt[node];
    float acc[8] = {};
    for (int j0 = 0; j0 < c; j0 += 64) {
        int m = min(64, c - j0);
        int2 e = make_int2(0, 0);
        if (lane < m) e = csr[s + j0 + lane];   // lanes >= m: r=0, w=0 -> no-op edges
        int ng = (m + 7) >> 3;
        int g = 0;
        for (; g + 4 <= ng; g += 4) {
            int s0 = g * 8 + es;
            int r0 = __shfl(e.x, s0);
            float w0 = __int_as_float(__shfl(e.y, s0));
            int r1 = __shfl(e.x, s0 + 8);
            float w1 = __int_as_float(__shfl(e.y, s0 + 8));
            int r2 = __shfl(e.x, s0 + 16);
            float w2 = __int_as_float(__shfl(e.y, s0 + 16));
            int r3 = __shfl(e.x, s0 + 24);
            float w3 = __int_as_float(__shfl(e.y, s0 + 24));
            int4 d0 = *(const int4*)(h1t + (((size_t)r0) << 6) + (fb << 3));
            int4 d1 = *(const int4*)(h1t + (((size_t)r1) << 6) + (fb << 3));
            int4 d2 = *(const int4*)(h1t + (((size_t)r2) << 6) + (fb << 3));
            int4 d3 = *(const int4*)(h1t + (((size_t)r3) << 6) + (fb << 3));
            acc[0] = fmaf(w0, bfl(d0.x), acc[0]);
            acc[1] = fmaf(w0, bfh(d0.x), acc[1]);
            acc[2] = fmaf(w0, bfl(d0.y), acc[2]);
            acc[3] = fmaf(w0, bfh(d0.y), acc[3]);
            acc[4] = fmaf(w0, bfl(d0.z), acc[4]);
            acc[5] = fmaf(w0, bfh(d0.z), acc[5]);
            acc[6] = fmaf(w0, bfl(d0.w), acc[6]);
            acc[7] = fmaf(w0, bfh(d0.w), acc[7]);
            acc[0] = fmaf(w1, bfl(d1.x), acc[0]);
            acc[1] = fmaf(w1, bfh(d1.x), acc[1]);
            acc[2] = fmaf(w1, bfl(d1.y), acc[2]);
            acc[3] = fmaf(w1, bfh(d1.y), acc[3]);
            acc[4] = fmaf(w1, bfl(d1.z), acc[4]);
            acc[5] = fmaf(w1, bfh(d1.z), acc[5]);
            acc[6] = fmaf(w1, bfl(d1.w), acc[6]);
            acc[7] = fmaf(w1, bfh(d1.w), acc[7]);
            acc[0] = fmaf(w2, bfl(d2.x), acc[0]);
            acc[1] = fmaf(w2, bfh(d2.x), acc[1]);
            acc[2] = fmaf(w2, bfl(d2.y), acc[2]);
            acc[3] = fmaf(w2, bfh(d2.y), acc[3]);
            acc[4] = fmaf(w2, bfl(d2.z), acc[4]);
            acc[5] = fmaf(w2, bfh(d2.z), acc[5]);
            acc[6] = fmaf(w2, bfl(d2.w), acc[6]);
            acc[7] = fmaf(w2, bfh(d2.w), acc[7]);
            acc[0] = fmaf(w3, bfl(d3.x), acc[0]);
            acc[1] = fmaf(w3, bfh(d3.x), acc[1]);
            acc[2] = fmaf(w3, bfl(d3.y), acc[2]);
            acc[3] = fmaf(w3, bfh(d3.y), acc[3]);
            acc[4] = fmaf(w3, bfl(d3.z), acc[4]);
            acc[5] = fmaf(w3, bfh(d3.z), acc[5]);
            acc[6] = fmaf(w3, bfl(d3.w), acc[6]);
            acc[7] = fmaf(w3, bfh(d3.w), acc[7]);
        }
        for (; g < ng; ++g) {
            int s0 = g * 8 + es;
            int r0 = __shfl(e.x, s0);
            float w0 = __int_as_float(__shfl(e.y, s0));
            int4 d0 = *(const int4*)(h1t + (((size_t)r0) << 6) + (fb << 3));
            acc[0] = fmaf(w0, bfl(d0.x), acc[0]);
            acc[1] = fmaf(w0, bfh(d0.x), acc[1]);
            acc[2] = fmaf(w0, bfl(d0.y), acc[2]);
            acc[3] = fmaf(w0, bfh(d0.y), acc[3]);
            acc[4] = fmaf(w0, bfl(d0.z), acc[4]);
            acc[5] = fmaf(w0, bfh(d0.z), acc[5]);
            acc[6] = fmaf(w0, bfl(d0.w), acc[6]);
            acc[7] = fmaf(w0, bfh(d0.w), acc[7]);
        }
    }
    #pragma unroll
    for (int mask = 8; mask <= 32; mask <<= 1) {
        #pragma unroll
        for (int k = 0; k < 8; ++k) acc[k] += __shfl_xor(acc[k], mask);
    }
    if (es == 0) {  // lanes 0..7; fb == lane; feats fb*8 .. fb*8+7
        float di = dinv[node];
        int4 ds = *(const int4*)(h1t + (((size_t)node) << 6) + (fb << 3));
        float4 bv0 = *(const float4*)&b1[fb * 8];
        float4 bv1 = *(const float4*)&b1[fb * 8 + 4];
        float4 o0, o1;
        o0.x = fmaxf(fmaf(acc[0] + bfl(ds.x), di, bv0.x), 0.f);
        o0.y = fmaxf(fmaf(acc[1] + bfh(ds.x), di, bv0.y), 0.f);
        o0.z = fmaxf(fmaf(acc[2] + bfl(ds.y), di, bv0.z), 0.f);
        o0.w = fmaxf(fmaf(acc[3] + bfh(ds.y), di, bv0.w), 0.f);
        o1.x = fmaxf(fmaf(acc[4] + bfl(ds.z), di, bv1.x), 0.f);
        o1.y = fmaxf(fmaf(acc[5] + bfh(ds.z), di, bv1.y), 0.f);
        o1.z = fmaxf(fmaf(acc[6] + bfl(ds.w), di, bv1.z), 0.f);
        o1.w = fmaxf(fmaf(acc[7] + bfh(ds.w), di, bv1.w), 0.f);
        float* po = h1p + (size_t)node * 64 + fb * 8;
        *(float4*)po = o0;
        *(float4*)(po + 4) = o1;
    }
}

// ---------------- aggregation conv2: 32 feats, half-wave per node ----------------
__global__ __launch_bounds__(256) void agg2_kernel(const int2* __restrict__ csr,
                                                   const int* __restrict__ off,
                                                   const int* __restrict__ cnt,
                                                   const float* __restrict__ dinv,
                                                   const unsigned short* __restrict__ h2t,
                                                   const float* __restrict__ b2,
                                                   float* __restrict__ h2p) {
    int lane = threadIdx.x & 63;
    int half = lane >> 5;
    int hl = lane & 31;
    int es = hl >> 2;   // edge slot 0..7
    int fb = hl & 3;    // feat block 0..3 (8 feats each)
    int wid = threadIdx.x >> 6;
    int node = blockIdx.x * 8 + wid * 2 + half;
    int s = off[node], c = cnt[node];
    int lbase = half << 5;
    float acc[8] = {};
    for (int j0 = 0; j0 < c; j0 += 32) {
        int m = min(32, c - j0);
        int2 e = make_int2(0, 0);
        if (hl < m) e = csr[s + j0 + hl];
        int ng = (m + 7) >> 3;
        int g = 0;
        for (; g + 2 <= ng; g += 2) {
            int s0 = lbase + g * 8 + es;
            int s1 = s0 + 8;
            int r0 = __shfl(e.x, s0);
            float w0 = __int_as_float(__shfl(e.y, s0));
            int r1 = __shfl(e.x, s1);
            float w1 = __int_as_float(__shfl(e.y, s1));
            int4 d0 = *(const int4*)(h2t + (((size_t)r0) << 5) + (fb << 3));
            int4 d1 = *(const int4*)(h2t + (((size_t)r1) << 5) + (fb << 3));
            acc[0] = fmaf(w0, bfl(d0.x), acc[0]);
            acc[1] = fmaf(w0, bfh(d0.x), acc[1]);
            acc[2] = fmaf(w0, bfl(d0.y), acc[2]);
            acc[3] = fmaf(w0, bfh(d0.y), acc[3]);
            acc[4] = fmaf(w0, bfl(d0.z), acc[4]);
            acc[5] = fmaf(w0, bfh(d0.z), acc[5]);
            acc[6] = fmaf(w0, bfl(d0.w), acc[6]);
            acc[7] = fmaf(w0, bfh(d0.w), acc[7]);
            acc[0] = fmaf(w1, bfl(d1.x), acc[0]);
            acc[1] = fmaf(w1, bfh(d1.x), acc[1]);
            acc[2] = fmaf(w1, bfl(d1.y), acc[2]);
            acc[3] = fmaf(w1, bfh(d1.y), acc[3]);
            acc[4] = fmaf(w1, bfl(d1.z), acc[4]);
            acc[5] = fmaf(w1, bfh(d1.z), acc[5]);
            acc[6] = fmaf(w1, bfl(d1.w), acc[6]);
            acc[7] = fmaf(w1, bfh(d1.w), acc[7]);
        }
        if (g < ng) {
            int s0 = lbase + g * 8 + es;
            int r0 = __shfl(e.x, s0);
            float w0 = __int_as_float(__shfl(e.y, s0));
            int4 d0 = *(const int4*)(h2t + (((size_t)r0) << 5) + (fb << 3));
            acc[0] = fmaf(w0, bfl(d0.x), acc[0]);
            acc[1] = fmaf(w0, bfh(d0.x), acc[1]);
            acc[2] = fmaf(w0, bfl(d0.y), acc[2]);
            acc[3] = fmaf(w0, bfh(d0.y), acc[3]);
            acc[4] = fmaf(w0, bfl(d0.z), acc[4]);
            acc[5] = fmaf(w0, bfh(d0.z), acc[5]);
            acc[6] = fmaf(w0, bfl(d0.w), acc[6]);
            acc[7] = fmaf(w0, bfh(d0.w), acc[7]);
        }
    }
    #pragma unroll
    for (int mask = 4; mask <= 16; mask <<= 1) {
        #pragma unroll
        for (int k = 0; k < 8; ++k) acc[k] += __shfl_xor(acc[k], mask);
    }
    if (es == 0) {  // hl 0..3; fb == hl; feats fb*8 .. fb*8+7
        float di = dinv[node];
        int4 ds = *(const int4*)(h2t + (((size_t)node) << 5) + (fb << 3));
        float4 bv0 = *(const float4*)&b2[fb * 8];
        float4 bv1 = *(const float4*)&b2[fb * 8 + 4];
        float4 o0, o1;
        o0.x = fmaf(acc[0] + bfl(ds.x), di, bv0.x);
        o0.y = fmaf(acc[1] + bfh(ds.x), di, bv0.y);
        o0.z = fmaf(acc[2] + bfl(ds.y), di, bv0.z);
        o0.w = fmaf(acc[3] + bfh(ds.y), di, bv0.w);
        o1.x = fmaf(acc[4] + bfl(ds.z), di, bv1.x);
        o1.y = fmaf(acc[5] + bfh(ds.z), di, bv1.y);
        o1.z = fmaf(acc[6] + bfl(ds.w), di, bv1.z);
        o1.w = fmaf(acc[7] + bfh(ds.w), di, bv1.w);
        float* po = h2p + (size_t)node * 32 + fb * 8;
        *(float4*)po = o0;
        *(float4*)(po + 4) = o1;
    }
}

// ---------------- pool: one block per graph (batch is sorted) ----------------
__global__ __launch_bounds__(256) void pool_kernel(const float* __restrict__ h2p,
                                                   const int* __restrict__ batch,
                                                   float* __restrict__ u) {
    int g = blockIdx.x;
    int lo = 0, hi = N_NODES;
    while (lo < hi) { int m = (lo + hi) >> 1; if (batch[m] < g) lo = m + 1; else hi = m; }
    int start = lo;
    hi = N_NODES;
    while (lo < hi) { int m = (lo + hi) >> 1; if (batch[m] < g + 1) lo = m + 1; else hi = m; }
    int end = lo;
    int f = threadIdx.x & 31, grp = threadIdx.x >> 5;
    float acc = 0.f;
    for (int n = start + grp; n < end; n += 8) acc += h2p[(size_t)n * 32 + f];
    __shared__ float red[8][32];
    red[grp][f] = acc;
    __syncthreads();
    if (threadIdx.x < 32) {
        float sum = 0.f;
        #pragma unroll
        for (int k = 0; k < 8; ++k) sum += red[k][threadIdx.x];
        u[g * 32 + threadIdx.x] = sum;
    }
}

// ---------------- MLP head ----------------
__global__ __launch_bounds__(256) void head_kernel(const float* __restrict__ u,
                                                   const float* __restrict__ Wl1,
                                                   const float* __restrict__ bl1,
                                                   const float* __restrict__ Wl2,
                                                   const float* __restrict__ bl2,
                                                   float* __restrict__ out) {
    int g = threadIdx.x;
    float uu[32];
    #pragma unroll
    for (int k = 0; k < 32; ++k) uu[k] = u[g * 32 + k];
    float o = bl2[0];
    #pragma unroll
    for (int j = 0; j < 16; ++j) {
        float h = bl1[j];
        #pragma unroll
        for (int k = 0; k < 32; ++k) h = fmaf(uu[k], Wl1[k * 16 + j], h);
        o = fmaf(fmaxf(h, 0.f), Wl2[j], o);
    }
    out[g] = o;
}

extern "C" void kernel_launch(void* const* d_in, const int* in_sizes, int n_in,
                              void* d_out, int out_size, void* d_ws, size_t ws_size,
                              hipStream_t stream) {
    const float* x     = (const float*)d_in[0];
    const int*   ei    = (const int*)d_in[1];
    const float* ew    = (const float*)d_in[2];
    const int*   batch = (const int*)d_in[3];
    const float* W1    = (const float*)d_in[4];
    const float* b1    = (const float*)d_in[5];
    const float* W2    = (const float*)d_in[6];
    const float* b2    = (const float*)d_in[7];
    const float* Wl1   = (const float*)d_in[8];
    const float* bl1   = (const float*)d_in[9];
    const float* Wl2   = (const float*)d_in[10];
    const float* bl2   = (const float*)d_in[11];
    float* out = (float*)d_out;

    const int* row = ei;
    const int* col = ei + N_EDGES;

    char* p = (char*)d_ws;
    auto alloc = [&](size_t bytes) {
        char* q = p;
        p += (bytes + 255) & ~(size_t)255;
        return q;
    };
    int*   btot   = (int*)alloc(NBUCK * 4);
    int*   bstart = (int*)alloc((NBUCK + 1) * 4);
    int*   gcur   = (int*)alloc(NBUCK * 4);
    int2*  rw2    = (int2*)alloc((size_t)N_EDGES * 8);
    int*   off    = (int*)alloc(N_NODES * 4);
    int*   cnt    = (int*)alloc(N_NODES * 4);
    float* dinv   = (float*)alloc(N_NODES * 4);
    int2*  csr    = (int2*)alloc((size_t)N_EDGES * 8);
    unsigned short* h1t = (unsigned short*)rw2;  // alias: rw2 dead after build (12.8 MB < 25.6 MB)
    float* h1p    = (float*)alloc((size_t)N_NODES * 64 * 4);
    unsigned short* h2t = (unsigned short*)alloc((size_t)N_NODES * 32 * 2);
    float* h2p    = (float*)alloc((size_t)N_NODES * 32 * 4);
    float* u      = (float*)alloc(N_GRAPHS * 32 * 4);

    hipMemsetAsync(btot, 0, NBUCK * 4, stream);
    hist_kernel<<<NB_SORT, 256, 0, stream>>>(col, btot);
    scan_buckets_kernel<<<1, 256, 0, stream>>>(btot, bstart, gcur);
    scatter_sort_kernel<<<NB_SORT, 256, 0, stream>>>(col, row, ew, gcur, rw2);
    build_kernel<<<NBUCK, 256, 0, stream>>>(bstart, rw2, off, cnt, dinv, csr);

    gemm_bf16_kernel<128, 64, 128><<<(N_NODES + 127) / 128, 256, 0, stream>>>(x, W1, dinv, h1t, N_NODES);
    agg1_kernel<<<N_NODES / 4, 256, 0, stream>>>(csr, off, cnt, dinv, h1t, b1, h1p);
    gemm_bf16_kernel<64, 32, 256><<<(N_NODES + 255) / 256, 256, 0, stream>>>(h1p, W2, dinv, h2t, N_NODES);
    agg2_kernel<<<N_NODES / 8, 256, 0, stream>>>(csr, off, cnt, dinv, h2t, b2, h2p);
    pool_kernel<<<N_GRAPHS, 256, 0, stream>>>(h2p, batch, u);
    head_kernel<<<1, 256, 0, stream>>>(u, Wl1, bl1, Wl2, bl2, out);
}